// Round 1
// baseline (78.221 us; speedup 1.0000x reference)
//
#include <hip/hip_runtime.h>

typedef unsigned short u16;
typedef __attribute__((ext_vector_type(8))) __bf16 bf16x8;
typedef __attribute__((ext_vector_type(4))) float f32x4;

#define GLOAD_LDS16(g, l)                                                                     \
  __builtin_amdgcn_global_load_lds((const __attribute__((address_space(1))) unsigned int*)(g), \
                                   (__attribute__((address_space(3))) unsigned int*)(l), 16, 0, 0)

static __device__ __forceinline__ u16 f2bf(float f) {
  unsigned int u = __float_as_uint(f);
  u += 0x7fffu + ((u >> 16) & 1u);   // round-to-nearest-even
  return (u16)(u >> 16);
}

// Constants for this problem instance
#define BATCH 32
#define NN 1024   // transform length (K and M of the GEMM)
#define MM 512    // columns (N of the GEMM)

// ---- kernel 1: DCT-III matrix, bf16, Mm[j][k] ----
// Mm[j][0] = 1/sqrt(n); Mm[j][k] = sqrt(2/n)*cos(pi*k*(2j+1)/(2n))
__global__ void fill_m(u16* __restrict__ Mm) {
  int idx = blockIdx.x * 256 + threadIdx.x;
  if (idx >= NN * NN) return;
  int j = idx >> 10;
  int k = idx & (NN - 1);
  float v;
  if (k == 0) {
    v = 0.03125f;  // 1/sqrt(1024)
  } else {
    int p = (k * (2 * j + 1)) & 4095;              // phase mod 4096 (cos period)
    float ang = (float)p * 1.5339807878856412e-3f; // pi/2048
    v = 0.04419417382415922f * cosf(ang);          // sqrt(2/1024) * cos
  }
  Mm[idx] = f2bf(v);
}

// ---- kernel 2: transpose + convert: x[B][n][m] f32 -> xt[B][m][n] bf16 ----
__global__ void conv_t(const float* __restrict__ x, u16* __restrict__ xt) {
  __shared__ u16 tile[32][34];  // [c][k], padded (stride 68B = 17 banks)
  const int b = blockIdx.z;
  const int k0 = blockIdx.y << 5;
  const int c0 = blockIdx.x << 5;
  const int t = threadIdx.x;
  {
    const int r = t >> 3;          // k row 0..31
    const int c4 = (t & 7) << 2;   // col 0..28 step 4
    const float4 v = *(const float4*)(x + ((size_t)b * NN + k0 + r) * MM + c0 + c4);
    tile[c4 + 0][r] = f2bf(v.x);
    tile[c4 + 1][r] = f2bf(v.y);
    tile[c4 + 2][r] = f2bf(v.z);
    tile[c4 + 3][r] = f2bf(v.w);
  }
  __syncthreads();
  {
    const int c = t >> 3;
    const int ko = (t & 7) << 2;
    ushort4 o;
    o.x = tile[c][ko + 0];
    o.y = tile[c][ko + 1];
    o.z = tile[c][ko + 2];
    o.w = tile[c][ko + 3];
    *(ushort4*)(xt + ((size_t)b * MM + c0 + c) * NN + k0 + ko) = o;
  }
}

// ---- kernel 3: batched GEMM C[b] = Mm * X[b], bf16 MFMA, fp32 out ----
// A = Mm [NN][NN] row-major (j,k); Bt = xt [B][MM][NN] row-major (c,k); C [B][NN][MM]
__global__ __launch_bounds__(256) void gemm_idct(const u16* __restrict__ A,
                                                 const u16* __restrict__ Bt,
                                                 float* __restrict__ C) {
  __shared__ u16 sA[128 * 32];  // [row j 0..127][k 0..31]
  __shared__ u16 sB[128 * 32];  // [col c 0..127][k 0..31]
  const int b  = blockIdx.z;
  const int tn = blockIdx.x;  // N tile (c), 0..3
  const int tm = blockIdx.y;  // M tile (j), 0..7
  const int t  = threadIdx.x;
  const int wave = t >> 6, lane = t & 63;
  const int wr = wave >> 1, wc = wave & 1;   // wave sub-tile 64x64
  const int lhi = lane >> 4, llo = lane & 15;

  // staging map: thread t -> row (t>>2), 16B chunk (t&3); LDS dest = t*16 bytes (linear)
  const int sr = t >> 2;
  const int sc = (t & 3) << 3;  // u16 offset in row

  const u16* gA = A + ((size_t)(tm * 128 + sr)) * NN + sc;
  const u16* gB = Bt + ((size_t)b * MM + tn * 128 + sr) * NN + sc;

  f32x4 acc[4][4] = {};

  for (int kt = 0; kt < NN; kt += 32) {
    GLOAD_LDS16(gA + kt,                     &sA[t * 8]);
    GLOAD_LDS16(gA + kt + (size_t)64 * NN,   &sA[2048 + t * 8]);
    GLOAD_LDS16(gB + kt,                     &sB[t * 8]);
    GLOAD_LDS16(gB + kt + (size_t)64 * NN,   &sB[2048 + t * 8]);
    __syncthreads();  // vmcnt(0) drain + barrier: tiles ready

    bf16x8 af[4], bfr[4];
#pragma unroll
    for (int i = 0; i < 4; ++i) {
      af[i]  = *(const bf16x8*)&sA[(wr * 64 + i * 16 + llo) * 32 + lhi * 8];
      bfr[i] = *(const bf16x8*)&sB[(wc * 64 + i * 16 + llo) * 32 + lhi * 8];
    }
#pragma unroll
    for (int mi = 0; mi < 4; ++mi)
#pragma unroll
      for (int ni = 0; ni < 4; ++ni)
        acc[mi][ni] =
            __builtin_amdgcn_mfma_f32_16x16x32_bf16(af[mi], bfr[ni], acc[mi][ni], 0, 0, 0);
    __syncthreads();  // protect LDS before next stage
  }

  // C/D layout (m89-verified): col = lane&15, row = (lane>>4)*4 + reg
  float* Cb = C + (size_t)b * NN * MM;
  const int j0 = tm * 128 + wr * 64 + lhi * 4;
  const int c0 = tn * 128 + wc * 64 + llo;
#pragma unroll
  for (int mi = 0; mi < 4; ++mi)
#pragma unroll
    for (int ni = 0; ni < 4; ++ni) {
      const int j = j0 + mi * 16;
      const int c = c0 + ni * 16;
#pragma unroll
      for (int r = 0; r < 4; ++r) Cb[(size_t)(j + r) * MM + c] = acc[mi][ni][r];
    }
}

extern "C" void kernel_launch(void* const* d_in, const int* in_sizes, int n_in,
                              void* d_out, int out_size, void* d_ws, size_t ws_size,
                              hipStream_t stream) {
  const float* x = (const float*)d_in[0];
  float* out = (float*)d_out;
  u16* Mm = (u16*)d_ws;                          // NN*NN u16 = 2 MiB
  u16* xt = (u16*)d_ws + (size_t)NN * NN;        // BATCH*MM*NN u16 = 32 MiB

  fill_m<<<dim3((NN * NN) / 256), dim3(256), 0, stream>>>(Mm);
  conv_t<<<dim3(MM / 32, NN / 32, BATCH), dim3(256), 0, stream>>>(x, xt);
  gemm_idct<<<dim3(MM / 128, NN / 128, BATCH), dim3(256), 0, stream>>>(Mm, xt, out);
}

// Round 2
// 66.809 us; speedup vs baseline: 1.1708x; 1.1708x over previous
//
#include <hip/hip_runtime.h>

typedef unsigned short u16;
typedef __attribute__((ext_vector_type(8))) __bf16 bf16x8;
typedef __attribute__((ext_vector_type(4))) float f32x4;

#define GLOAD_LDS16(g, l)                                                                     \
  __builtin_amdgcn_global_load_lds((const __attribute__((address_space(1))) unsigned int*)(g), \
                                   (__attribute__((address_space(3))) unsigned int*)(l), 16, 0, 0)

static __device__ __forceinline__ u16 f2bf(float f) {
  unsigned int u = __float_as_uint(f);
  u += 0x7fffu + ((u >> 16) & 1u);   // round-to-nearest-even
  return (u16)(u >> 16);
}

// Constants for this problem instance
#define BATCH 32
#define NN 1024   // transform length (K and M of the GEMM)
#define MM 512    // columns (N of the GEMM)

// ---- kernel 1: DCT-III matrix, bf16, Mm[j][k] ----
__global__ void fill_m(u16* __restrict__ Mm) {
  int idx = blockIdx.x * 256 + threadIdx.x;
  if (idx >= NN * NN) return;
  int j = idx >> 10;
  int k = idx & (NN - 1);
  float v;
  if (k == 0) {
    v = 0.03125f;  // 1/sqrt(1024)
  } else {
    int p = (k * (2 * j + 1)) & 4095;              // phase mod 4096 (cos period)
    float ang = (float)p * 1.5339807878856412e-3f; // pi/2048
    v = 0.04419417382415922f * cosf(ang);          // sqrt(2/1024) * cos
  }
  Mm[idx] = f2bf(v);
}

// ---- kernel 2: transpose + convert: x[B][n][m] f32 -> xt[B][m][n] bf16 ----
__global__ void conv_t(const float* __restrict__ x, u16* __restrict__ xt) {
  __shared__ u16 tile[32][34];
  const int b = blockIdx.z;
  const int k0 = blockIdx.y << 5;
  const int c0 = blockIdx.x << 5;
  const int t = threadIdx.x;
  {
    const int r = t >> 3;
    const int c4 = (t & 7) << 2;
    const float4 v = *(const float4*)(x + ((size_t)b * NN + k0 + r) * MM + c0 + c4);
    tile[c4 + 0][r] = f2bf(v.x);
    tile[c4 + 1][r] = f2bf(v.y);
    tile[c4 + 2][r] = f2bf(v.z);
    tile[c4 + 3][r] = f2bf(v.w);
  }
  __syncthreads();
  {
    const int c = t >> 3;
    const int ko = (t & 7) << 2;
    ushort4 o;
    o.x = tile[c][ko + 0];
    o.y = tile[c][ko + 1];
    o.z = tile[c][ko + 2];
    o.w = tile[c][ko + 3];
    *(ushort4*)(xt + ((size_t)b * MM + c0 + c) * NN + k0 + ko) = o;
  }
}

// ---- kernel 3: batched GEMM C[b] = Mm * X[b], bf16 MFMA, fp32 out ----
// BK=64, XOR-swizzled LDS (pre-swizzled global source; linear global_load_lds dest).
// LDS tile [128 rows][64 k] u16, row = 128 B = 32 banks.
// Physical 16B-chunk pc of row r holds DATA chunk pc ^ (r&7).
__global__ __launch_bounds__(256) void gemm_idct(const u16* __restrict__ A,
                                                 const u16* __restrict__ Bt,
                                                 float* __restrict__ C) {
  __shared__ u16 sA[128 * 64];  // 16 KiB
  __shared__ u16 sB[128 * 64];  // 16 KiB
  const int b  = blockIdx.z;
  const int tn = blockIdx.x;  // N tile (c), 0..3
  const int tm = blockIdx.y;  // M tile (j), 0..7
  const int t  = threadIdx.x;
  const int wave = t >> 6, lane = t & 63;
  const int wr = wave >> 1, wc = wave & 1;   // wave sub-tile 64x64
  const int lhi = lane >> 4, llo = lane & 15;

  // staging map: call c stages rows c*32 .. c*32+31.
  // thread t -> row-in-group rA = t>>3, physical chunk pc = t&7,
  // data chunk dc = pc ^ (row&7) = (t&7) ^ ((t>>3)&7)  (row ≡ rA mod 8).
  const int rA = t >> 3;
  const int dc = (t & 7) ^ (rA & 7);

  const u16* gA = A + (size_t)(tm * 128 + rA) * NN + dc * 8;
  const u16* gB = Bt + ((size_t)b * MM + tn * 128 + rA) * NN + dc * 8;

  f32x4 acc[4][4] = {};

  for (int kt = 0; kt < NN; kt += 64) {
#pragma unroll
    for (int c = 0; c < 4; ++c) {
      GLOAD_LDS16(gA + kt + (size_t)(c * 32) * NN, &sA[c * 2048 + t * 8]);
      GLOAD_LDS16(gB + kt + (size_t)(c * 32) * NN, &sB[c * 2048 + t * 8]);
    }
    __syncthreads();  // vmcnt(0) drain + barrier: tiles ready

#pragma unroll
    for (int w = 0; w < 2; ++w) {
      bf16x8 af[4], bfr[4];
#pragma unroll
      for (int i = 0; i < 4; ++i) {
        const int ra = wr * 64 + i * 16 + llo;
        const int rb = wc * 64 + i * 16 + llo;
        const int ca = (((w << 2) | lhi) ^ (llo & 7)) << 3;  // swizzled chunk * 8
        af[i]  = *(const bf16x8*)&sA[ra * 64 + ca];
        bfr[i] = *(const bf16x8*)&sB[rb * 64 + ca];
      }
#pragma unroll
      for (int mi = 0; mi < 4; ++mi)
#pragma unroll
        for (int ni = 0; ni < 4; ++ni)
          acc[mi][ni] =
              __builtin_amdgcn_mfma_f32_16x16x32_bf16(af[mi], bfr[ni], acc[mi][ni], 0, 0, 0);
    }
    __syncthreads();  // protect LDS before next stage
  }

  // C/D layout (m89-verified): col = lane&15, row = (lane>>4)*4 + reg
  float* Cb = C + (size_t)b * NN * MM;
  const int j0 = tm * 128 + wr * 64 + lhi * 4;
  const int c0 = tn * 128 + wc * 64 + llo;
#pragma unroll
  for (int mi = 0; mi < 4; ++mi)
#pragma unroll
    for (int ni = 0; ni < 4; ++ni) {
      const int j = j0 + mi * 16;
      const int c = c0 + ni * 16;
#pragma unroll
      for (int r = 0; r < 4; ++r) Cb[(size_t)(j + r) * MM + c] = acc[mi][ni][r];
    }
}

extern "C" void kernel_launch(void* const* d_in, const int* in_sizes, int n_in,
                              void* d_out, int out_size, void* d_ws, size_t ws_size,
                              hipStream_t stream) {
  const float* x = (const float*)d_in[0];
  float* out = (float*)d_out;
  u16* Mm = (u16*)d_ws;                          // NN*NN u16 = 2 MiB
  u16* xt = (u16*)d_ws + (size_t)NN * NN;        // BATCH*MM*NN u16 = 32 MiB

  fill_m<<<dim3((NN * NN) / 256), dim3(256), 0, stream>>>(Mm);
  conv_t<<<dim3(MM / 32, NN / 32, BATCH), dim3(256), 0, stream>>>(x, xt);
  gemm_idct<<<dim3(MM / 128, NN / 128, BATCH), dim3(256), 0, stream>>>(Mm, xt, out);
}

// Round 3
// 62.327 us; speedup vs baseline: 1.2550x; 1.0719x over previous
//
#include <hip/hip_runtime.h>

typedef unsigned short u16;
typedef __attribute__((ext_vector_type(8))) __bf16 bf16x8;
typedef __attribute__((ext_vector_type(4))) float f32x4;

#define GLOAD_LDS16(g, l)                                                                     \
  __builtin_amdgcn_global_load_lds((const __attribute__((address_space(1))) unsigned int*)(g), \
                                   (__attribute__((address_space(3))) unsigned int*)(l), 16, 0, 0)

static __device__ __forceinline__ u16 f2bf(float f) {
  unsigned int u = __float_as_uint(f);
  u += 0x7fffu + ((u >> 16) & 1u);   // round-to-nearest-even
  return (u16)(u >> 16);
}

// Constants for this problem instance
#define BATCH 32
#define NN 1024   // transform length (K and M of the GEMM)
#define MM 512    // columns (N of the GEMM)

// ---- kernel 1: DCT-III matrix, bf16, Mm[j][k] ----
__global__ void fill_m(u16* __restrict__ Mm) {
  int idx = blockIdx.x * 256 + threadIdx.x;
  if (idx >= NN * NN) return;
  int j = idx >> 10;
  int k = idx & (NN - 1);
  float v;
  if (k == 0) {
    v = 0.03125f;  // 1/sqrt(1024)
  } else {
    int p = (k * (2 * j + 1)) & 4095;              // phase mod 4096 (cos period)
    float ang = (float)p * 1.5339807878856412e-3f; // pi/2048
    v = 0.04419417382415922f * cosf(ang);          // sqrt(2/1024) * cos
  }
  Mm[idx] = f2bf(v);
}

// ---- kernel 2: transpose + convert: x[B][n][m] f32 -> xt[B][m][n] bf16 ----
__global__ void conv_t(const float* __restrict__ x, u16* __restrict__ xt) {
  __shared__ u16 tile[32][34];
  const int b = blockIdx.z;
  const int k0 = blockIdx.y << 5;
  const int c0 = blockIdx.x << 5;
  const int t = threadIdx.x;
  {
    const int r = t >> 3;
    const int c4 = (t & 7) << 2;
    const float4 v = *(const float4*)(x + ((size_t)b * NN + k0 + r) * MM + c0 + c4);
    tile[c4 + 0][r] = f2bf(v.x);
    tile[c4 + 1][r] = f2bf(v.y);
    tile[c4 + 2][r] = f2bf(v.z);
    tile[c4 + 3][r] = f2bf(v.w);
  }
  __syncthreads();
  {
    const int c = t >> 3;
    const int ko = (t & 7) << 2;
    ushort4 o;
    o.x = tile[c][ko + 0];
    o.y = tile[c][ko + 1];
    o.z = tile[c][ko + 2];
    o.w = tile[c][ko + 3];
    *(ushort4*)(xt + ((size_t)b * MM + c0 + c) * NN + k0 + ko) = o;
  }
}

// ---- kernel 3: 256x256x(BK=64) 8-wave GEMM, 4-phase/tile counted-vmcnt pipeline ----
// C[b] = Mm * X[b].  A = Mm[j][k]; Bt = xt[b][c][k]; both k-contiguous.
// LDS: 2 buffers x {A[256][64], B[256][64]} bf16, XOR-swizzled rows (chunk pc holds
// data chunk pc ^ (row&7)); staged via pre-swizzled global source, linear gload_lds dest.
// Tile t lives in buf[t&1]. Phase q of tile t: MFMA C-quadrant q (A rows [q*64,q*64+64)).
// Issue schedule (per thread, region-safe by construction):
//   P0: A-slice3(t+1) -> buf[t+1&1]   (region freed at t-1's P3 barrier)
//   P1: B0(t+2),B1(t+2),A0(t+2) -> buf[t&1]  (freed at t's P0 barrier)
//   P2: B2(t+2),A1(t+2)                       (freed at t's P1 barrier)
//   P3: B3(t+2),A2(t+2)                       (freed at t's P2 barrier)
// Gate: vmcnt(7) at each tile's P3 (youngest piece of tile t+1 = A3(t+1)@tP0,
// exactly 7 loads issued after it) — never drains to 0 until the epilogue.
__global__ __launch_bounds__(512, 2) void gemm_idct(const u16* __restrict__ A,
                                                    const u16* __restrict__ Bt,
                                                    float* __restrict__ C) {
  __shared__ __align__(16) u16 lds[2][2][16384];  // [buf][A/B][256*64], 128 KiB
  const int b  = blockIdx.z;
  const int tn = blockIdx.x;  // N tile (c), 0..1
  const int tm = blockIdx.y;  // M tile (j), 0..3
  const int t512 = threadIdx.x;
  const int wave = t512 >> 6, lane = t512 & 63;
  const int wm = wave >> 2, wn = wave & 3;   // 2 x 4 waves; per-wave out 128x64
  const int lhi = lane >> 4, llo = lane & 15;

  // staging map: thread -> row-in-slice srow=t>>3 (0..63), physical chunk spc=t&7,
  // pre-swizzled data chunk sdc = spc ^ (srow&7).
  const int srow = t512 >> 3;
  const int spc  = t512 & 7;
  const int sdc  = spc ^ (srow & 7);

  const u16* gA = A + (size_t)(tm * 256 + srow) * NN + sdc * 8;
  const u16* gB = Bt + ((size_t)b * MM + tn * 256 + srow) * NN + sdc * 8;

#define ISSUE_A(buf, q, tt) GLOAD_LDS16(gA + (size_t)(q) * 64 * NN + (tt) * 64, \
                                        &lds[buf][0][(q) * 4096 + t512 * 8])
#define ISSUE_B(buf, p, tt) GLOAD_LDS16(gB + (size_t)(p) * 64 * NN + (tt) * 64, \
                                        &lds[buf][1][(p) * 4096 + t512 * 8])

  // ---- prologue: tile0 (8 pieces) then tile1 minus A3 (7 pieces) ----
#pragma unroll
  for (int p = 0; p < 4; ++p) ISSUE_B(0, p, 0);
#pragma unroll
  for (int q = 0; q < 4; ++q) ISSUE_A(0, q, 0);
#pragma unroll
  for (int p = 0; p < 4; ++p) ISSUE_B(1, p, 1);
  ISSUE_A(1, 0, 1);
  ISSUE_A(1, 1, 1);
  ISSUE_A(1, 2, 1);
  asm volatile("s_waitcnt vmcnt(7)" ::: "memory");  // 15 issued, <=7 out -> tile0 landed
  __builtin_amdgcn_s_barrier();
  __builtin_amdgcn_sched_barrier(0);

  f32x4 acc[8][4] = {};
  bf16x8 bfr[4][2];

  for (int t = 0; t < 16; ++t) {
    const int cur = t & 1, nxt = cur ^ 1;
    const u16* lA = &lds[cur][0][0];
    const u16* lB = &lds[cur][1][0];
#pragma unroll
    for (int q = 0; q < 4; ++q) {
      // --- prefetch issues (region freed by previous phase's barrier) ---
      if (q == 0) {
        if (t < 15) ISSUE_A(nxt, 3, t + 1);
      } else if (q == 1) {
        if (t < 14) { ISSUE_B(cur, 0, t + 2); ISSUE_B(cur, 1, t + 2); ISSUE_A(cur, 0, t + 2); }
      } else if (q == 2) {
        if (t < 14) { ISSUE_B(cur, 2, t + 2); ISSUE_A(cur, 1, t + 2); }
      } else {
        if (t < 14) { ISSUE_B(cur, 3, t + 2); ISSUE_A(cur, 2, t + 2); }
      }
      // --- register fragments (compiler manages lgkmcnt before MFMA use) ---
      if (q == 0) {
#pragma unroll
        for (int nf = 0; nf < 4; ++nf)
#pragma unroll
          for (int ks = 0; ks < 2; ++ks) {
            const int rb = wn * 64 + nf * 16 + llo;
            bfr[nf][ks] = *(const bf16x8*)&lB[rb * 64 + ((((ks << 2) | lhi)) ^ (llo & 7)) * 8];
          }
      }
      bf16x8 af[2][2];
#pragma unroll
      for (int mf = 0; mf < 2; ++mf)
#pragma unroll
        for (int ks = 0; ks < 2; ++ks) {
          const int ra = q * 64 + wm * 32 + mf * 16 + llo;
          af[mf][ks] = *(const bf16x8*)&lA[ra * 64 + (((ks << 2) | lhi) ^ (llo & 7)) * 8];
        }
      // --- 16 MFMA (quadrant q x K=64) ---
      __builtin_amdgcn_s_setprio(1);
#pragma unroll
      for (int mf = 0; mf < 2; ++mf)
#pragma unroll
        for (int nf = 0; nf < 4; ++nf)
#pragma unroll
          for (int ks = 0; ks < 2; ++ks)
            acc[(q << 1) | mf][nf] = __builtin_amdgcn_mfma_f32_16x16x32_bf16(
                af[mf][ks], bfr[nf][ks], acc[(q << 1) | mf][nf], 0, 0, 0);
      __builtin_amdgcn_s_setprio(0);
      // --- tile-boundary gate (counted; covers all of tile t+1) + phase barrier ---
      if (q == 3) {
        if (t < 14)
          asm volatile("s_waitcnt vmcnt(7)" ::: "memory");
        else if (t == 14)
          asm volatile("s_waitcnt vmcnt(0)" ::: "memory");
      }
      __builtin_amdgcn_s_barrier();
      __builtin_amdgcn_sched_barrier(0);
    }
  }

  // ---- epilogue: C/D layout col=lane&15, row=(lane>>4)*4+reg ----
  float* Cb = C + (size_t)b * NN * MM;
  const int jbase = tm * 256 + wm * 32 + lhi * 4;
  const int cbase = tn * 256 + wn * 64 + llo;
#pragma unroll
  for (int q = 0; q < 4; ++q)
#pragma unroll
    for (int mf = 0; mf < 2; ++mf)
#pragma unroll
      for (int nf = 0; nf < 4; ++nf) {
        const int j = jbase + q * 64 + mf * 16;
        const int c = cbase + nf * 16;
#pragma unroll
        for (int r = 0; r < 4; ++r)
          Cb[(size_t)(j + r) * MM + c] = acc[(q << 1) | mf][nf][r];
      }
#undef ISSUE_A
#undef ISSUE_B
}

extern "C" void kernel_launch(void* const* d_in, const int* in_sizes, int n_in,
                              void* d_out, int out_size, void* d_ws, size_t ws_size,
                              hipStream_t stream) {
  const float* x = (const float*)d_in[0];
  float* out = (float*)d_out;
  u16* Mm = (u16*)d_ws;                          // NN*NN u16 = 2 MiB
  u16* xt = (u16*)d_ws + (size_t)NN * NN;        // BATCH*MM*NN u16 = 32 MiB

  fill_m<<<dim3((NN * NN) / 256), dim3(256), 0, stream>>>(Mm);
  conv_t<<<dim3(MM / 32, NN / 32, BATCH), dim3(256), 0, stream>>>(x, xt);
  gemm_idct<<<dim3(MM / 256, NN / 256, BATCH), dim3(512), 0, stream>>>(Mm, xt, out);
}